// Round 1
// baseline (1295.430 us; speedup 1.0000x reference)
//
#include <hip/hip_runtime.h>
#include <cstdint>
#include <cstddef>

// Problem constants (from reference)
#define B_    2
#define S_    4096
#define H_    2048
#define D2_   1024
#define SCALE_ 0.125f

typedef __attribute__((ext_vector_type(8))) short short8;
typedef __attribute__((ext_vector_type(4))) float f32x4;

// round-to-nearest-even fp32 -> bf16 (as ushort)
__device__ __forceinline__ ushort f2bf(float f) {
    union { float f; uint32_t u; } c; c.f = f;
    uint32_t u = c.u;
    u += 0x7fffu + ((u >> 16) & 1u);
    return (ushort)(u >> 16);
}

// ---------------- elementwise cast fp32 -> bf16, n4 = n/4 ----------------
__global__ __launch_bounds__(256) void cast_bf16_kernel(const float* __restrict__ src,
                                                        ushort* __restrict__ dst, int n4) {
    int i = blockIdx.x * 256 + threadIdx.x;
    if (i < n4) {
        float4 v = ((const float4*)src)[i];
        ushort4 o;
        o.x = f2bf(v.x); o.y = f2bf(v.y); o.z = f2bf(v.z); o.w = f2bf(v.w);
        ((ushort4*)dst)[i] = o;
    }
}

// ---------------- GEMM: C[M,N] = alpha * A[M,K] * B[N,K]^T (bf16 in, fp32 out) ----
// 128x128 tile, BK=32, 4 waves (2x2), each wave 64x64 via 4x4 of 16x16x32 MFMA.
#define BM 128
#define BN 128
#define BK 32
__global__ __launch_bounds__(256) void gemm_nt(const ushort* __restrict__ A,
                                               const ushort* __restrict__ B,
                                               float* __restrict__ C,
                                               int M, int N, int K, float alpha) {
    __shared__ __align__(16) ushort As[BM * BK];
    __shared__ __align__(16) ushort Bs[BN * BK];
    const int tid  = threadIdx.x;
    const int lane = tid & 63;
    const int wave = tid >> 6;
    const int wm = (wave >> 1) * 64;
    const int wn = (wave & 1) * 64;
    const int bm = blockIdx.y * BM;
    const int bn = blockIdx.x * BN;
    const int col  = lane & 15;
    const int quad = lane >> 4;

    f32x4 acc[4][4];
#pragma unroll
    for (int i = 0; i < 4; i++)
#pragma unroll
        for (int j = 0; j < 4; j++) { f32x4 z = {0.f, 0.f, 0.f, 0.f}; acc[i][j] = z; }

    // staging: 512 chunks of 16B per tile; thread t does chunks t and t+256
    const int r0 = tid >> 2;          // row 0..63
    const int k0 = (tid & 3) * 8;     // element offset within row

    for (int kt = 0; kt < K; kt += BK) {
        uint4 a0 = *(const uint4*)(A + (size_t)(bm + r0) * K + kt + k0);
        uint4 a1 = *(const uint4*)(A + (size_t)(bm + r0 + 64) * K + kt + k0);
        uint4 b0 = *(const uint4*)(B + (size_t)(bn + r0) * K + kt + k0);
        uint4 b1 = *(const uint4*)(B + (size_t)(bn + r0 + 64) * K + kt + k0);
        __syncthreads();
        ((uint4*)As)[tid]       = a0;
        ((uint4*)As)[tid + 256] = a1;
        ((uint4*)Bs)[tid]       = b0;
        ((uint4*)Bs)[tid + 256] = b1;
        __syncthreads();

        short8 af[4], bf[4];
#pragma unroll
        for (int mi = 0; mi < 4; mi++)
            af[mi] = ((const short8*)As)[(wm + mi * 16 + col) * 4 + quad];
#pragma unroll
        for (int ni = 0; ni < 4; ni++)
            bf[ni] = ((const short8*)Bs)[(wn + ni * 16 + col) * 4 + quad];
#pragma unroll
        for (int mi = 0; mi < 4; mi++)
#pragma unroll
            for (int ni = 0; ni < 4; ni++)
                acc[mi][ni] = __builtin_amdgcn_mfma_f32_16x16x32_bf16(af[mi], bf[ni], acc[mi][ni], 0, 0, 0);
    }

    // C/D layout: col = lane&15, row = quad*4 + reg   [measured m89/m91]
#pragma unroll
    for (int mi = 0; mi < 4; mi++)
#pragma unroll
        for (int ni = 0; ni < 4; ni++)
#pragma unroll
            for (int r = 0; r < 4; r++) {
                int grow = bm + wm + mi * 16 + quad * 4 + r;
                int gcol = bn + wn + ni * 16 + col;
                C[(size_t)grow * N + gcol] = alpha * acc[mi][ni][r];
            }
}

// ---------------- RoPE: interleaved out, bf16 q_rot/k_rot + fp32 k_rot -----------
__global__ __launch_bounds__(256) void rope_kernel(const float* __restrict__ qf,
                                                   const float* __restrict__ kf,
                                                   const float* __restrict__ cosT,
                                                   const float* __restrict__ sinT,
                                                   const int* __restrict__ pos,
                                                   ushort* __restrict__ qr,
                                                   ushort* __restrict__ kr,
                                                   float* __restrict__ krf32) {
    int row = blockIdx.x;            // 0 .. B*S-1
    int s = row & (S_ - 1);
    int p = pos[s];
    const float* q  = qf + (size_t)row * H_;
    const float* k  = kf + (size_t)row * H_;
    const float* cr = cosT + (size_t)p * D2_;
    const float* sr = sinT + (size_t)p * D2_;
    ushort* qro = qr + (size_t)row * H_;
    ushort* kro = kr + (size_t)row * H_;
    float* krf  = krf32 + (size_t)row * H_;
    for (int j = threadIdx.x; j < D2_; j += 256) {
        float c = cr[j], sn = sr[j];
        float xr = q[j], xi = q[j + D2_];
        float o0 = xr * c - xi * sn;
        float o1 = xr * sn + xi * c;
        ushort2 uq; uq.x = f2bf(o0); uq.y = f2bf(o1);
        ((ushort2*)qro)[j] = uq;                      // elements 2j, 2j+1
        float yr = k[j], yi = k[j + D2_];
        float p0 = yr * c - yi * sn;
        float p1 = yr * sn + yi * c;
        ushort2 uk; uk.x = f2bf(p0); uk.y = f2bf(p1);
        ((ushort2*)kro)[j] = uk;
        float2 fk; fk.x = p0; fk.y = p1;
        ((float2*)krf)[j] = fk;
    }
}

// ---------------- transpose+cast: v[b][s][h] fp32 -> vt[b][h][s] bf16 ------------
__global__ __launch_bounds__(256) void transpose_cast_kernel(const float* __restrict__ v,
                                                             ushort* __restrict__ vt) {
    __shared__ float tile[32][33];
    int b  = blockIdx.z;
    int s0 = blockIdx.y * 32, h0 = blockIdx.x * 32;
    const float* vb = v + (size_t)b * S_ * H_;
    ushort* vtb = vt + (size_t)b * H_ * S_;
    int tx = threadIdx.x & 31, ty = threadIdx.x >> 5;
#pragma unroll
    for (int i = 0; i < 32; i += 8)
        tile[ty + i][tx] = vb[(size_t)(s0 + ty + i) * H_ + h0 + tx];
    __syncthreads();
#pragma unroll
    for (int i = 0; i < 32; i += 8)
        vtb[(size_t)(h0 + ty + i) * S_ + s0 + tx] = f2bf(tile[tx][ty + i]);
}

// ---------------- row softmax: fp32 scores (4096 wide) -> bf16 probs -------------
__global__ __launch_bounds__(256) void softmax_kernel(const float* __restrict__ sc,
                                                      ushort* __restrict__ pr) {
    __shared__ float red[8];
    size_t row = blockIdx.x;
    const float4* r = (const float4*)(sc + row * (size_t)S_);
    int tid = threadIdx.x;
    float4 v[4];
    float m = -1e30f;
#pragma unroll
    for (int i = 0; i < 4; i++) {
        v[i] = r[tid + i * 256];
        m = fmaxf(m, fmaxf(fmaxf(v[i].x, v[i].y), fmaxf(v[i].z, v[i].w)));
    }
#pragma unroll
    for (int off = 32; off >= 1; off >>= 1) m = fmaxf(m, __shfl_xor(m, off));
    if ((tid & 63) == 0) red[tid >> 6] = m;
    __syncthreads();
    m = fmaxf(fmaxf(red[0], red[1]), fmaxf(red[2], red[3]));
    float s = 0.f;
#pragma unroll
    for (int i = 0; i < 4; i++) {
        v[i].x = __expf(v[i].x - m); v[i].y = __expf(v[i].y - m);
        v[i].z = __expf(v[i].z - m); v[i].w = __expf(v[i].w - m);
        s += v[i].x + v[i].y + v[i].z + v[i].w;
    }
#pragma unroll
    for (int off = 32; off >= 1; off >>= 1) s += __shfl_xor(s, off);
    if ((tid & 63) == 0) red[4 + (tid >> 6)] = s;
    __syncthreads();
    float inv = 1.0f / (red[4] + red[5] + red[6] + red[7]);
    ushort4* o = (ushort4*)(pr + row * (size_t)S_);
#pragma unroll
    for (int i = 0; i < 4; i++) {
        ushort4 u;
        u.x = f2bf(v[i].x * inv); u.y = f2bf(v[i].y * inv);
        u.z = f2bf(v[i].z * inv); u.w = f2bf(v[i].w * inv);
        o[tid + i * 256] = u;
    }
}

// =================================================================================
extern "C" void kernel_launch(void* const* d_in, const int* in_sizes, int n_in,
                              void* d_out, int out_size, void* d_ws, size_t ws_size,
                              hipStream_t stream) {
    const float* hs   = (const float*)d_in[0];
    const float* wq   = (const float*)d_in[1];
    const float* wk   = (const float*)d_in[2];
    const float* wv   = (const float*)d_in[3];
    const float* wo   = (const float*)d_in[4];
    const float* fcos = (const float*)d_in[5];
    const float* fsin = (const float*)d_in[6];
    const int*   pos  = (const int*)d_in[7];

    const size_t BSH = (size_t)B_ * S_ * H_;   // 16,777,216
    const size_t HH  = (size_t)H_ * H_;        //  4,194,304

    float* out      = (float*)d_out;           // [0]       output (B,S,H)
    float* krot_out = out + BSH;               // [1]       k_rot  (B,S,H)
    float* v_out    = krot_out + BSH;          // [2]       v      (B,S,H)

    // workspace layout (MB offsets), with reuse:
    //  [0,32)   Xb bf16        [32,64)  weights bf16
    //  [64,192) q_f32/k_f32 -> scores fp32 -> ctx f32 [64,128) + ctx bf16 [128,160)
    //  [192,224) q_rot bf16   [224,256) k_rot bf16   [256,288) vT bf16   [288,352) probs bf16
    char* ws = (char*)d_ws;
    const size_t MB = 1ull << 20;
    ushort* Xb  = (ushort*)(ws + 0);
    ushort* Wqb = (ushort*)(ws + 32 * MB);
    ushort* Wkb = (ushort*)(ws + 40 * MB);
    ushort* Wvb = (ushort*)(ws + 48 * MB);
    ushort* Wob = (ushort*)(ws + 56 * MB);
    float*  qf  = (float*)(ws + 64 * MB);
    float*  kf  = (float*)(ws + 128 * MB);
    float*  sc  = (float*)(ws + 64 * MB);      // reuse (q/k fp32 dead after rope)
    ushort* qrb = (ushort*)(ws + 192 * MB);
    ushort* krb = (ushort*)(ws + 224 * MB);
    ushort* vtb = (ushort*)(ws + 256 * MB);
    ushort* prb = (ushort*)(ws + 288 * MB);
    float*  cf  = (float*)(ws + 64 * MB);      // reuse (scores dead after softmax)
    ushort* cb  = (ushort*)(ws + 128 * MB);    // reuse

    // 1. casts to bf16
    cast_bf16_kernel<<<(int)(BSH / 4 / 256), 256, 0, stream>>>(hs, Xb, (int)(BSH / 4));
    cast_bf16_kernel<<<(int)(HH / 4 / 256), 256, 0, stream>>>(wq, Wqb, (int)(HH / 4));
    cast_bf16_kernel<<<(int)(HH / 4 / 256), 256, 0, stream>>>(wk, Wkb, (int)(HH / 4));
    cast_bf16_kernel<<<(int)(HH / 4 / 256), 256, 0, stream>>>(wv, Wvb, (int)(HH / 4));
    cast_bf16_kernel<<<(int)(HH / 4 / 256), 256, 0, stream>>>(wo, Wob, (int)(HH / 4));

    // 2. Q/K/V projections (C = X * W^T)
    dim3 gProj(H_ / BN, (B_ * S_) / BM);       // (16, 64)
    gemm_nt<<<gProj, 256, 0, stream>>>(Xb, Wqb, qf,    B_ * S_, H_, H_, 1.0f);
    gemm_nt<<<gProj, 256, 0, stream>>>(Xb, Wkb, kf,    B_ * S_, H_, H_, 1.0f);
    gemm_nt<<<gProj, 256, 0, stream>>>(Xb, Wvb, v_out, B_ * S_, H_, H_, 1.0f);

    // 3. RoPE (writes k_rot fp32 output + bf16 copies for attention)
    rope_kernel<<<B_ * S_, 256, 0, stream>>>(qf, kf, fcos, fsin, pos, qrb, krb, krot_out);

    // 4. v^T in bf16 for the PV GEMM
    transpose_cast_kernel<<<dim3(H_ / 32, S_ / 32, B_), 256, 0, stream>>>(v_out, vtb);

    // 5. scores = SCALE * q_rot k_rot^T, per batch
    dim3 gSc(S_ / BN, S_ / BM);                // (32, 32)
    for (int b = 0; b < B_; b++)
        gemm_nt<<<gSc, 256, 0, stream>>>(qrb + (size_t)b * S_ * H_,
                                         krb + (size_t)b * S_ * H_,
                                         sc + (size_t)b * S_ * S_, S_, S_, H_, SCALE_);

    // 6. softmax rows -> bf16 probs
    softmax_kernel<<<B_ * S_, 256, 0, stream>>>(sc, prb);

    // 7. ctx = probs @ v  (as probs * (v^T)^T)
    dim3 gPV(H_ / BN, S_ / BM);                // (16, 32)
    for (int b = 0; b < B_; b++)
        gemm_nt<<<gPV, 256, 0, stream>>>(prb + (size_t)b * S_ * S_,
                                         vtb + (size_t)b * H_ * S_,
                                         cf + (size_t)b * S_ * H_, S_, H_, S_, 1.0f);

    // 8. ctx -> bf16, then output projection
    cast_bf16_kernel<<<(int)(BSH / 4 / 256), 256, 0, stream>>>(cf, cb, (int)(BSH / 4));
    gemm_nt<<<gProj, 256, 0, stream>>>(cb, Wob, out, B_ * S_, H_, H_, 1.0f);
}

// Round 2
// 1292.776 us; speedup vs baseline: 1.0021x; 1.0021x over previous
//
#include <hip/hip_runtime.h>
#include <cstdint>
#include <cstddef>

// Problem constants (from reference)
#define B_    2
#define S_    4096
#define H_    2048
#define D2_   1024
#define SCALE_ 0.125f

typedef __attribute__((ext_vector_type(8))) _Float16 half8;
typedef __attribute__((ext_vector_type(4))) float f32x4;

// fp32 -> fp16 (RNE) as ushort bits
__device__ __forceinline__ ushort f2h(float f) {
    _Float16 h = (_Float16)f;
    return *(ushort*)&h;
}
__device__ __forceinline__ float h2f(ushort u) {
    return (float)(*(_Float16*)&u);
}

// async 16B global -> LDS (wave-uniform base + lane*16 semantics)
__device__ __forceinline__ void gld_lds16(const ushort* g, ushort* l) {
    __builtin_amdgcn_global_load_lds((const __attribute__((address_space(1))) void*)g,
                                     (__attribute__((address_space(3))) void*)l,
                                     16, 0, 0);
}

// ---------------- elementwise cast fp32 -> fp16, n4 = n/4 ----------------
__global__ __launch_bounds__(256) void cast_f16_kernel(const float* __restrict__ src,
                                                       ushort* __restrict__ dst, int n4) {
    int i = blockIdx.x * 256 + threadIdx.x;
    if (i < n4) {
        float4 v = ((const float4*)src)[i];
        ushort4 o;
        o.x = f2h(v.x); o.y = f2h(v.y); o.z = f2h(v.z); o.w = f2h(v.w);
        ((ushort4*)dst)[i] = o;
    }
}

// fused cast of the 4 weight matrices (each n4 float4 chunks)
__global__ __launch_bounds__(256) void cast4_f16_kernel(const float* __restrict__ w0,
                                                        const float* __restrict__ w1,
                                                        const float* __restrict__ w2,
                                                        const float* __restrict__ w3,
                                                        ushort* __restrict__ o0,
                                                        ushort* __restrict__ o1,
                                                        ushort* __restrict__ o2,
                                                        ushort* __restrict__ o3,
                                                        int n4) {
    int i = blockIdx.x * 256 + threadIdx.x;
    if (i >= n4) return;
    const float* s; ushort* d;
    switch (blockIdx.y) {
        case 0: s = w0; d = o0; break;
        case 1: s = w1; d = o1; break;
        case 2: s = w2; d = o2; break;
        default: s = w3; d = o3; break;
    }
    float4 v = ((const float4*)s)[i];
    ushort4 o;
    o.x = f2h(v.x); o.y = f2h(v.y); o.z = f2h(v.z); o.w = f2h(v.w);
    ((ushort4*)d)[i] = o;
}

// ---------------- GEMM: C[M,N] = alpha * A[M,K] * B[N,K]^T (f16 in, f32/f16 out) --
// 128x128 tile, BK=32, 4 waves (2x2), each wave 64x64 via 4x4 of 16x16x32 MFMA.
// Staging via global_load_lds width=16 (m97 structure, ~874 TF verified ladder).
#define BM 128
#define BN 128
#define BK 32
template <bool HALF_OUT>
__global__ __launch_bounds__(256) void gemm_nt(const ushort* __restrict__ A,
                                               const ushort* __restrict__ B,
                                               void* __restrict__ Cv,
                                               int M, int N, int K, float alpha) {
    __shared__ __align__(16) ushort As[BM * BK];
    __shared__ __align__(16) ushort Bs[BN * BK];
    const int tid  = threadIdx.x;
    const int lane = tid & 63;
    const int wave = tid >> 6;
    const int wm = (wave >> 1) * 64;
    const int wn = (wave & 1) * 64;
    const int bm = blockIdx.y * BM;
    const int bn = blockIdx.x * BN;
    const int col  = lane & 15;
    const int quad = lane >> 4;

    f32x4 acc[4][4];
#pragma unroll
    for (int i = 0; i < 4; i++)
#pragma unroll
        for (int j = 0; j < 4; j++) { f32x4 z = {0.f, 0.f, 0.f, 0.f}; acc[i][j] = z; }

    // chunk layout: chunk t = 16B at As+t*16; row = t>>2, k = (t&3)*8.
    // Wave w, lane l -> chunk w*64+l: contiguous => global_load_lds-compatible.
    const int r0 = tid >> 2;
    const int k0 = (tid & 3) * 8;
    const ushort* gA  = A + (size_t)(bm + r0) * K + k0;
    const ushort* gA2 = gA + (size_t)64 * K;
    const ushort* gB  = B + (size_t)(bn + r0) * K + k0;
    const ushort* gB2 = gB + (size_t)64 * K;
    ushort* lA  = As + tid * 8;          // byte offset tid*16
    ushort* lA2 = lA + 256 * 8;
    ushort* lB  = Bs + tid * 8;
    ushort* lB2 = lB + 256 * 8;

    for (int kt = 0; kt < K; kt += BK) {
        __syncthreads();                 // prior tile's LDS reads complete
        gld_lds16(gA + kt, lA);
        gld_lds16(gA2 + kt, lA2);
        gld_lds16(gB + kt, lB);
        gld_lds16(gB2 + kt, lB2);
        __syncthreads();                 // drains vmcnt -> LDS valid

        half8 af[4], bf[4];
#pragma unroll
        for (int mi = 0; mi < 4; mi++)
            af[mi] = ((const half8*)As)[(wm + mi * 16 + col) * 4 + quad];
#pragma unroll
        for (int ni = 0; ni < 4; ni++)
            bf[ni] = ((const half8*)Bs)[(wn + ni * 16 + col) * 4 + quad];
#pragma unroll
        for (int mi = 0; mi < 4; mi++)
#pragma unroll
            for (int ni = 0; ni < 4; ni++)
                acc[mi][ni] = __builtin_amdgcn_mfma_f32_16x16x32_f16(af[mi], bf[ni], acc[mi][ni], 0, 0, 0);
    }

    // C/D layout: col = lane&15, row = quad*4 + reg   [measured m89/m91]
#pragma unroll
    for (int mi = 0; mi < 4; mi++)
#pragma unroll
        for (int ni = 0; ni < 4; ni++)
#pragma unroll
            for (int r = 0; r < 4; r++) {
                int grow = bm + wm + mi * 16 + quad * 4 + r;
                int gcol = bn + wn + ni * 16 + col;
                float val = alpha * acc[mi][ni][r];
                if (HALF_OUT)
                    ((ushort*)Cv)[(size_t)grow * N + gcol] = f2h(val);
                else
                    ((float*)Cv)[(size_t)grow * N + gcol] = val;
            }
}

// ---------------- RoPE: f16 q,k in; interleaved f16 q_rot/k_rot + fp32 k_rot ------
// One thread handles 4 consecutive j (vectorized 8B/16B loads+stores).
__global__ __launch_bounds__(256) void rope_kernel(const ushort* __restrict__ qh,
                                                   const ushort* __restrict__ kh,
                                                   const float* __restrict__ cosT,
                                                   const float* __restrict__ sinT,
                                                   const int* __restrict__ pos,
                                                   ushort* __restrict__ qr,
                                                   ushort* __restrict__ kr,
                                                   float* __restrict__ krf32) {
    int idx = blockIdx.x * 256 + threadIdx.x;       // B*S*(D2/4) total
    int row = idx >> 8;                             // D2_/4 == 256
    int jj  = (idx & 255) * 4;
    int p = pos[row & (S_ - 1)];
    const ushort* q = qh + (size_t)row * H_ + jj;
    const ushort* k = kh + (size_t)row * H_ + jj;
    const float* cr = cosT + (size_t)p * D2_ + jj;
    const float* sr = sinT + (size_t)p * D2_ + jj;
    float4 c = *(const float4*)cr;
    float4 sn = *(const float4*)sr;
    ushort4 qr4 = *(const ushort4*)q;
    ushort4 qi4 = *(const ushort4*)(q + D2_);
    ushort4 kr4 = *(const ushort4*)k;
    ushort4 ki4 = *(const ushort4*)(k + D2_);

    float qrv[4] = {h2f(qr4.x), h2f(qr4.y), h2f(qr4.z), h2f(qr4.w)};
    float qiv[4] = {h2f(qi4.x), h2f(qi4.y), h2f(qi4.z), h2f(qi4.w)};
    float krv[4] = {h2f(kr4.x), h2f(kr4.y), h2f(kr4.z), h2f(kr4.w)};
    float kiv[4] = {h2f(ki4.x), h2f(ki4.y), h2f(ki4.z), h2f(ki4.w)};
    float cv[4] = {c.x, c.y, c.z, c.w};
    float sv[4] = {sn.x, sn.y, sn.z, sn.w};

    ushort qo[8], ko[8];
    float kf[8];
#pragma unroll
    for (int t = 0; t < 4; t++) {
        float o0 = qrv[t] * cv[t] - qiv[t] * sv[t];
        float o1 = qrv[t] * sv[t] + qiv[t] * cv[t];
        qo[2 * t] = f2h(o0); qo[2 * t + 1] = f2h(o1);
        float p0 = krv[t] * cv[t] - kiv[t] * sv[t];
        float p1 = krv[t] * sv[t] + kiv[t] * cv[t];
        ko[2 * t] = f2h(p0); ko[2 * t + 1] = f2h(p1);
        kf[2 * t] = p0; kf[2 * t + 1] = p1;
    }
    ushort* qro = qr + (size_t)row * H_ + 2 * jj;
    ushort* kro = kr + (size_t)row * H_ + 2 * jj;
    float* krf  = krf32 + (size_t)row * H_ + 2 * jj;
    *(ushort4*)(qro)     = *(ushort4*)(qo);
    *(ushort4*)(qro + 4) = *(ushort4*)(qo + 4);
    *(ushort4*)(kro)     = *(ushort4*)(ko);
    *(ushort4*)(kro + 4) = *(ushort4*)(ko + 4);
    *(float4*)(krf)      = *(float4*)(kf);
    *(float4*)(krf + 4)  = *(float4*)(kf + 4);
}

// ---------------- transpose+cast: v[b][s][h] fp32 -> vt[b][h][s] f16 ------------
__global__ __launch_bounds__(256) void transpose_cast_kernel(const float* __restrict__ v,
                                                             ushort* __restrict__ vt) {
    __shared__ float tile[32][33];
    int b  = blockIdx.z;
    int s0 = blockIdx.y * 32, h0 = blockIdx.x * 32;
    const float* vb = v + (size_t)b * S_ * H_;
    ushort* vtb = vt + (size_t)b * H_ * S_;
    int tx = threadIdx.x & 31, ty = threadIdx.x >> 5;
#pragma unroll
    for (int i = 0; i < 32; i += 8)
        tile[ty + i][tx] = vb[(size_t)(s0 + ty + i) * H_ + h0 + tx];
    __syncthreads();
#pragma unroll
    for (int i = 0; i < 32; i += 8)
        vtb[(size_t)(h0 + ty + i) * S_ + s0 + tx] = f2h(tile[tx][ty + i]);
}

// ---------------- row softmax: fp32 scores (4096 wide) -> f16 probs -------------
__global__ __launch_bounds__(256) void softmax_kernel(const float* __restrict__ sc,
                                                      ushort* __restrict__ pr) {
    __shared__ float red[8];
    size_t row = blockIdx.x;
    const float4* r = (const float4*)(sc + row * (size_t)S_);
    int tid = threadIdx.x;
    float4 v[4];
    float m = -1e30f;
#pragma unroll
    for (int i = 0; i < 4; i++) {
        v[i] = r[tid + i * 256];
        m = fmaxf(m, fmaxf(fmaxf(v[i].x, v[i].y), fmaxf(v[i].z, v[i].w)));
    }
#pragma unroll
    for (int off = 32; off >= 1; off >>= 1) m = fmaxf(m, __shfl_xor(m, off));
    if ((tid & 63) == 0) red[tid >> 6] = m;
    __syncthreads();
    m = fmaxf(fmaxf(red[0], red[1]), fmaxf(red[2], red[3]));
    float s = 0.f;
#pragma unroll
    for (int i = 0; i < 4; i++) {
        v[i].x = __expf(v[i].x - m); v[i].y = __expf(v[i].y - m);
        v[i].z = __expf(v[i].z - m); v[i].w = __expf(v[i].w - m);
        s += v[i].x + v[i].y + v[i].z + v[i].w;
    }
#pragma unroll
    for (int off = 32; off >= 1; off >>= 1) s += __shfl_xor(s, off);
    if ((tid & 63) == 0) red[4 + (tid >> 6)] = s;
    __syncthreads();
    float inv = 1.0f / (red[4] + red[5] + red[6] + red[7]);
    ushort4* o = (ushort4*)(pr + row * (size_t)S_);
#pragma unroll
    for (int i = 0; i < 4; i++) {
        ushort4 u;
        u.x = f2h(v[i].x * inv); u.y = f2h(v[i].y * inv);
        u.z = f2h(v[i].z * inv); u.w = f2h(v[i].w * inv);
        o[tid + i * 256] = u;
    }
}

// =================================================================================
extern "C" void kernel_launch(void* const* d_in, const int* in_sizes, int n_in,
                              void* d_out, int out_size, void* d_ws, size_t ws_size,
                              hipStream_t stream) {
    const float* hs   = (const float*)d_in[0];
    const float* wq   = (const float*)d_in[1];
    const float* wk   = (const float*)d_in[2];
    const float* wv   = (const float*)d_in[3];
    const float* wo   = (const float*)d_in[4];
    const float* fcos = (const float*)d_in[5];
    const float* fsin = (const float*)d_in[6];
    const int*   pos  = (const int*)d_in[7];

    const size_t BSH = (size_t)B_ * S_ * H_;   // 16,777,216
    const size_t HH  = (size_t)H_ * H_;        //  4,194,304

    float* out      = (float*)d_out;           // [0] output (B,S,H)
    float* krot_out = out + BSH;               // [1] k_rot  (B,S,H)
    float* v_out    = krot_out + BSH;          // [2] v      (B,S,H)

    // workspace layout (MB offsets), 352 MB total, with reuse:
    //  [0,32)    Xb f16
    //  [32,64)   Wq/Wk/Wv/Wo f16 (8 MB each)
    //  [64,128)  qh f16 [64,96) + kh f16 [96,128)  -> dead after rope -> prb f16
    //  [128,192) qrb f16 [128,160) + krb f16 [160,192) -> qrb area reused for cb f16
    //  [192,224) vT f16
    //  [224,352) scores fp32
    char* ws = (char*)d_ws;
    const size_t MB = 1ull << 20;
    ushort* Xb  = (ushort*)(ws + 0);
    ushort* Wqb = (ushort*)(ws + 32 * MB);
    ushort* Wkb = (ushort*)(ws + 40 * MB);
    ushort* Wvb = (ushort*)(ws + 48 * MB);
    ushort* Wob = (ushort*)(ws + 56 * MB);
    ushort* qh  = (ushort*)(ws + 64 * MB);
    ushort* kh  = (ushort*)(ws + 96 * MB);
    ushort* qrb = (ushort*)(ws + 128 * MB);
    ushort* krb = (ushort*)(ws + 160 * MB);
    ushort* vtb = (ushort*)(ws + 192 * MB);
    float*  sc  = (float*)(ws + 224 * MB);
    ushort* prb = (ushort*)(ws + 64 * MB);     // reuse qh+kh (dead after rope)
    ushort* cb  = (ushort*)(ws + 128 * MB);    // reuse qrb (dead after scores)

    // 1. casts to f16
    cast_f16_kernel<<<(int)(BSH / 4 / 256), 256, 0, stream>>>(hs, Xb, (int)(BSH / 4));
    cast4_f16_kernel<<<dim3((int)(HH / 4 / 256), 4), 256, 0, stream>>>(
        wq, wk, wv, wo, Wqb, Wkb, Wvb, Wob, (int)(HH / 4));

    // 2. Q/K/V projections (C = X * W^T); Q/K straight to f16, V to fp32 output
    dim3 gProj(H_ / BN, (B_ * S_) / BM);       // (16, 64)
    gemm_nt<true ><<<gProj, 256, 0, stream>>>(Xb, Wqb, qh,    B_ * S_, H_, H_, 1.0f);
    gemm_nt<true ><<<gProj, 256, 0, stream>>>(Xb, Wkb, kh,    B_ * S_, H_, H_, 1.0f);
    gemm_nt<false><<<gProj, 256, 0, stream>>>(Xb, Wvb, v_out, B_ * S_, H_, H_, 1.0f);

    // 3. RoPE (f16 q_rot/k_rot for attention + fp32 k_rot output)
    rope_kernel<<<(B_ * S_ * (D2_ / 4)) / 256, 256, 0, stream>>>(
        qh, kh, fcos, fsin, pos, qrb, krb, krot_out);

    // 4. v^T in f16 for the PV GEMM
    transpose_cast_kernel<<<dim3(H_ / 32, S_ / 32, B_), 256, 0, stream>>>(v_out, vtb);

    // 5. scores = SCALE * q_rot k_rot^T, per batch
    dim3 gSc(S_ / BN, S_ / BM);                // (32, 32)
    for (int b = 0; b < B_; b++)
        gemm_nt<false><<<gSc, 256, 0, stream>>>(qrb + (size_t)b * S_ * H_,
                                                krb + (size_t)b * S_ * H_,
                                                sc + (size_t)b * S_ * S_, S_, S_, H_, SCALE_);

    // 6. softmax rows -> f16 probs
    softmax_kernel<<<B_ * S_, 256, 0, stream>>>(sc, prb);

    // 7. ctx = probs @ v  (as probs * (v^T)^T), f16 out directly
    dim3 gPV(H_ / BN, S_ / BM);                // (16, 32)
    for (int b = 0; b < B_; b++)
        gemm_nt<true><<<gPV, 256, 0, stream>>>(prb + (size_t)b * S_ * S_,
                                               vtb + (size_t)b * H_ * S_,
                                               cb + (size_t)b * S_ * H_, S_, H_, S_, 1.0f);

    // 8. output projection
    gemm_nt<false><<<gProj, 256, 0, stream>>>(cb, Wob, out, B_ * S_, H_, H_, 1.0f);
}